// Round 3
// baseline (790.556 us; speedup 1.0000x reference)
//
#include <hip/hip_runtime.h>
#include <hip/hip_bf16.h>

#define NDIM 128

__device__ __forceinline__ float bf2f(__hip_bfloat16 v) { return __bfloat162float(v); }

// Read element i of a float array stored fp32 (f32!=0) or bf16 (f32==0).
__device__ __forceinline__ float ldf(const void* p, long i, int f32) {
    return f32 ? ((const float*)p)[i] : bf2f(((const __hip_bfloat16*)p)[i]);
}
// Store element i in the detected dtype.
__device__ __forceinline__ void stf(void* p, long i, int f32, float v) {
    if (f32) ((float*)p)[i] = v;
    else     ((__hip_bfloat16*)p)[i] = __float2bfloat16(v);
}

// ---- runtime dtype detection ----------------------------------------------
// flags[0]=eflag (xedge int64), flags[1]=yflag (y byte-packed), flags[2]=fflag (fp32)
__global__ void detect_kernel(const int* __restrict__ xedge32,
                              const unsigned int* __restrict__ yw,
                              const unsigned short* __restrict__ xh,
                              int* __restrict__ flags) {
    __shared__ int se, sy, scount;
    const int t = threadIdx.x;
    if (t == 0) { se = 1; sy = 0; scount = 0; }
    __syncthreads();
    // int64 edges => odd 32-bit words (high halves) all zero
    for (int i = t; i < 512; i += 256)
        if (xedge32[2 * i + 1] != 0) se = 0;
    // byte-packed bool y => some word has a set byte above byte0
    for (int i = t; i < 1024; i += 256)
        if (yw[i] > 1u) sy = 1;
    // bf16 floats => even halfwords have sane bf16 exponents for N(0,1) data
    int c = 0;
    for (int i = t; i < 1024; i += 256) {
        int ex = (xh[2 * i] >> 7) & 0xFF;
        if (ex >= 100 && ex <= 150) c++;
    }
    atomicAdd(&scount, c);
    __syncthreads();
    if (t == 0) {
        flags[0] = se;
        flags[1] = sy;
        flags[2] = (scount < 900) ? 1 : 0;
    }
}

// ---- CSR construction ------------------------------------------------------

__global__ void degree_kernel(const int* __restrict__ xedge, int E,
                              const int* __restrict__ flags, int* __restrict__ cnt) {
    int e = blockIdx.x * blockDim.x + threadIdx.x;
    if (e >= E) return;
    const int e64 = flags[0];
    int d = e64 ? xedge[2 * (E + e)] : xedge[E + e];
    atomicAdd(&cnt[d], 1);
}

// single-block exclusive scan; also zeroes cnt so fill can reuse it as cursor
__global__ void scan_kernel(int* __restrict__ cnt, int* __restrict__ rowptr, int N) {
    __shared__ int part[1024];
    const int t = threadIdx.x;
    const int chunk = (N + 1023) >> 10;
    const int base = t * chunk;
    int s = 0;
    for (int i = 0; i < chunk; ++i) { int idx = base + i; if (idx < N) s += cnt[idx]; }
    part[t] = s;
    __syncthreads();
    for (int off = 1; off < 1024; off <<= 1) {
        int v = (t >= off) ? part[t - off] : 0;
        __syncthreads();
        part[t] += v;
        __syncthreads();
    }
    int run = (t == 0) ? 0 : part[t - 1];
    for (int i = 0; i < chunk; ++i) {
        int idx = base + i;
        if (idx < N) { rowptr[idx] = run; run += cnt[idx]; cnt[idx] = 0; }
    }
    if (t == 1023) rowptr[N] = part[1023];
}

__global__ void fill_kernel(const int* __restrict__ xedge, int E,
                            const int* __restrict__ flags, const int* __restrict__ rowptr,
                            int* __restrict__ cur, int* __restrict__ col) {
    int e = blockIdx.x * blockDim.x + threadIdx.x;
    if (e >= E) return;
    const int e64 = flags[0];
    int s = e64 ? xedge[2 * e] : xedge[e];
    int d = e64 ? xedge[2 * (E + e)] : xedge[E + e];
    int p = rowptr[d] + atomicAdd(&cur[d], 1);
    col[p] = s;
}

// ---- fused SAGE layer: mean-aggregate (in LDS) + dense, 8 nodes/block ------
// XFLAG: input dtype follows flags[2]; else input is canonical bf16 (hbuf)
// OUTFLAG: output dtype follows flags[2] and out points at the emb region base
//          computation (d_out + elemsize); else output is canonical bf16.

template <bool XFLAG, bool RELU, bool OUTFLAG>
__global__ void fused_layer(const void* __restrict__ X, const int* __restrict__ rowptr,
                            const int* __restrict__ col,
                            const void* __restrict__ Wl, const void* __restrict__ bias,
                            const void* __restrict__ Wr, const int* __restrict__ flags,
                            void* __restrict__ out, int N) {
    __shared__ float Ms[8][NDIM];  // neighbor means
    __shared__ float Ss[8][NDIM];  // self features
    const int j = threadIdx.x;
    const int n0 = blockIdx.x * 8;
    const int wf = flags[2];
    const int xf = XFLAG ? wf : 0;
#pragma unroll
    for (int r = 0; r < 8; ++r) {
        int n = n0 + r;
        float m = 0.f, s = 0.f;
        if (n < N) {
            int b = rowptr[n], e = rowptr[n + 1];
            for (int i = b; i < e; ++i)
                m += ldf(X, (long)col[i] * NDIM + j, xf);
            m /= fmaxf((float)(e - b), 1.f);
            s = ldf(X, (long)n * NDIM + j, xf);
        }
        Ms[r][j] = m;
        Ss[r][j] = s;
    }
    __syncthreads();
    float acc[8];
    const float bv = ldf(bias, j, wf);
#pragma unroll
    for (int r = 0; r < 8; ++r) acc[r] = bv;
    for (int k0 = 0; k0 < NDIM; k0 += 4) {
        float wl[4], wr[4];
#pragma unroll
        for (int kk = 0; kk < 4; ++kk) {
            wl[kk] = ldf(Wl, (k0 + kk) * NDIM + j, wf);
            wr[kk] = ldf(Wr, (k0 + kk) * NDIM + j, wf);
        }
#pragma unroll
        for (int r = 0; r < 8; ++r) {
            const float4 a = *(const float4*)(&Ms[r][k0]);
            const float4 b = *(const float4*)(&Ss[r][k0]);
            acc[r] += a.x * wl[0] + a.y * wl[1] + a.z * wl[2] + a.w * wl[3]
                    + b.x * wr[0] + b.y * wr[1] + b.z * wr[2] + b.w * wr[3];
        }
    }
    void* ob = out;
    int of = 0;
    if (OUTFLAG) {
        of = wf;
        ob = (void*)((char*)out + (wf ? 4 : 2));  // emb region = d_out + 1 element
    }
#pragma unroll
    for (int r = 0; r < 8; ++r) {
        int n = n0 + r;
        if (n < N) {
            float v = acc[r];
            if (RELU) v = fmaxf(v, 0.f);
            stf(ob, (long)n * NDIM + j, of, v);
        }
    }
}

// ---- fused decoder + BCE-with-logits partial sums --------------------------
// emb is read back from the d_out emb region in the detected dtype.

__global__ void loss_kernel(const void* __restrict__ d_out_base,
                            const void* __restrict__ Wd, const void* __restrict__ yv,
                            const int* __restrict__ flags, float* __restrict__ accum,
                            int* __restrict__ npos, int N) {
    __shared__ float As[8][NDIM];
    const int j = threadIdx.x;
    const int n0 = blockIdx.x * 8;
    const int wf = flags[2];
    const int yb = flags[1];
    const void* emb = (const void*)((const char*)d_out_base + (wf ? 4 : 2));
#pragma unroll
    for (int r = 0; r < 8; ++r) {
        int n = n0 + r;
        As[r][j] = (n < N) ? ldf(emb, (long)n * NDIM + j, wf) : 0.f;
    }
    __syncthreads();
    float acc[8];
#pragma unroll
    for (int r = 0; r < 8; ++r) acc[r] = 0.f;
    for (int k0 = 0; k0 < NDIM; k0 += 4) {
        float wd[4];
#pragma unroll
        for (int kk = 0; kk < 4; ++kk) wd[kk] = ldf(Wd, (k0 + kk) * NDIM + j, wf);
#pragma unroll
        for (int r = 0; r < 8; ++r) {
            const float4 a = *(const float4*)(&As[r][k0]);
            acc[r] += a.x * wd[0] + a.y * wd[1] + a.z * wd[2] + a.w * wd[3];
        }
    }
    float lpos = 0.f, lneg = 0.f;
#pragma unroll
    for (int r = 0; r < 8; ++r) {
        int n = n0 + r;
        if (n < N) {
            int yn = yb ? (int)((const unsigned char*)yv)[n] : ((const int*)yv)[n];
            float z = acc[r];
            float L = log1pf(expf(-fabsf(z)));
            float spp = fmaxf(-z, 0.f) + L;  // softplus(-z)
            float spn = fmaxf(z, 0.f) + L;   // softplus(z)
            if (yn != 0) lpos += spp; else lneg += spn;
        }
    }
#pragma unroll
    for (int off = 32; off >= 1; off >>= 1) {
        lpos += __shfl_down(lpos, off, 64);
        lneg += __shfl_down(lneg, off, 64);
    }
    __shared__ float red[2][2];
    const int wave = j >> 6, lane = j & 63;
    if (lane == 0) { red[wave][0] = lpos; red[wave][1] = lneg; }
    __syncthreads();
    if (j == 0) {
        atomicAdd(&accum[0], red[0][0] + red[1][0]);
        atomicAdd(&accum[1], red[0][1] + red[1][1]);
        int c = 0;
#pragma unroll
        for (int r = 0; r < 8; ++r) {
            int n = n0 + r;
            if (n < N) {
                int yn = yb ? (int)((const unsigned char*)yv)[n] : ((const int*)yv)[n];
                if (yn != 0) c++;
            }
        }
        if (c) atomicAdd(npos, c);
    }
}

__global__ void finalize_kernel(const float* __restrict__ accum, const int* __restrict__ npos,
                                const int* __restrict__ flags, void* __restrict__ out, int N) {
    float np_ = (float)(*npos);
    float nn_ = (float)N - np_;
    float l2 = accum[0] / (fmaxf(np_, 1.f) * 128.f);
    float l1 = accum[1] / (fmaxf(nn_, 1.f) * 128.f);
    stf(out, 0, flags[2], l1 + l2);
}

// ---- launch ----------------------------------------------------------------

extern "C" void kernel_launch(void* const* d_in, const int* in_sizes, int n_in,
                              void* d_out, int out_size, void* d_ws, size_t ws_size,
                              hipStream_t stream) {
    const void* x    = d_in[0];
    const int* xedge = (const int*)d_in[1];
    const void* y    = d_in[2];
    // d_in[3] = pretrain (unused)
    const void* W1l  = d_in[4];
    const void* b1l  = d_in[5];
    const void* W1r  = d_in[6];
    const void* W2l  = d_in[7];
    const void* b2l  = d_in[8];
    const void* W2r  = d_in[9];
    const void* Wdec = d_in[10];

    const int N = in_sizes[0] / NDIM;
    const int E = in_sizes[1] / 2;

    char* ws = (char*)d_ws;
    size_t off = 0;
    auto alloc = [&](size_t bytes) -> void* {
        void* p = ws + off;
        off = (off + bytes + 255) & ~(size_t)255;
        return p;
    };
    int*   flags  = (int*)alloc(64);
    float* accum  = (float*)alloc(64);
    int*   npos   = (int*)alloc(64);
    int*   cnt    = (int*)alloc((size_t)N * 4);
    int*   rowptr = (int*)alloc((size_t)(N + 1) * 4);
    int*   col    = (int*)alloc((size_t)E * 4);
    __hip_bfloat16* hbuf = (__hip_bfloat16*)alloc((size_t)N * NDIM * 2);
    // total ws footprint ~16.6 MB

    hipMemsetAsync(cnt, 0, (size_t)N * 4, stream);
    hipMemsetAsync(accum, 0, 8, stream);
    hipMemsetAsync(npos, 0, 4, stream);

    detect_kernel<<<1, 256, 0, stream>>>(xedge, (const unsigned int*)y,
                                         (const unsigned short*)x, flags);

    const int eb = (E + 255) / 256;
    degree_kernel<<<eb, 256, 0, stream>>>(xedge, E, flags, cnt);
    scan_kernel<<<1, 1024, 0, stream>>>(cnt, rowptr, N);
    fill_kernel<<<eb, 256, 0, stream>>>(xedge, E, flags, rowptr, cnt, col);

    const int nb = (N + 7) / 8;
    // layer 1: input x (flag dtype) -> hbuf (bf16 canonical), relu
    fused_layer<true, true, false><<<nb, NDIM, 0, stream>>>(
        x, rowptr, col, W1l, b1l, W1r, flags, hbuf, N);
    // layer 2: input hbuf (bf16) -> emb region of d_out (flag dtype), no relu
    fused_layer<false, false, true><<<nb, NDIM, 0, stream>>>(
        hbuf, rowptr, col, W2l, b2l, W2r, flags, d_out, N);
    loss_kernel<<<nb, NDIM, 0, stream>>>(d_out, Wdec, y, flags, accum, npos, N);
    finalize_kernel<<<1, 1, 0, stream>>>(accum, npos, flags, d_out, N);
}

// Round 4
// 721.091 us; speedup vs baseline: 1.0963x; 1.0963x over previous
//
#include <hip/hip_runtime.h>
#include <hip/hip_bf16.h>

#define NDIM 128

typedef __attribute__((ext_vector_type(8))) short short8;
typedef __attribute__((ext_vector_type(4))) float f32x4;

__device__ __forceinline__ float bf2f(__hip_bfloat16 v) { return __bfloat162float(v); }

// Read element i of a float array stored fp32 (f32!=0) or bf16 (f32==0).
__device__ __forceinline__ float ldf(const void* p, long i, int f32) {
    return f32 ? ((const float*)p)[i] : bf2f(((const __hip_bfloat16*)p)[i]);
}
__device__ __forceinline__ void stf(void* p, long i, int f32, float v) {
    if (f32) ((float*)p)[i] = v;
    else     ((__hip_bfloat16*)p)[i] = __float2bfloat16(v);
}
__device__ __forceinline__ short f2bf(float v) {
    __hip_bfloat16 h = __float2bfloat16(v);
    short s;
    __builtin_memcpy(&s, &h, 2);
    return s;
}
// Swizzled LDS index for A-tiles: 16B-chunk XOR by (row&7) -> conflict-free
// ds_read_b128 fragment reads AND conflict-light gather-phase writes.
__device__ __forceinline__ int aswz(int m, int k) {
    return m * NDIM + ((((k >> 3) ^ (m & 7)) << 3) | (k & 7));
}

// ---- runtime dtype detection ----------------------------------------------
// flags[0]=eflag (xedge int64), flags[1]=yflag (y byte-packed), flags[2]=fflag (fp32)
__global__ void detect_kernel(const int* __restrict__ xedge32,
                              const unsigned int* __restrict__ yw,
                              const unsigned short* __restrict__ xh,
                              int* __restrict__ flags) {
    __shared__ int se, sy, scount;
    const int t = threadIdx.x;
    if (t == 0) { se = 1; sy = 0; scount = 0; }
    __syncthreads();
    for (int i = t; i < 512; i += 256)
        if (xedge32[2 * i + 1] != 0) se = 0;
    for (int i = t; i < 1024; i += 256)
        if (yw[i] > 1u) sy = 1;
    int c = 0;
    for (int i = t; i < 1024; i += 256) {
        int ex = (xh[2 * i] >> 7) & 0xFF;
        if (ex >= 100 && ex <= 150) c++;
    }
    atomicAdd(&scount, c);
    __syncthreads();
    if (t == 0) {
        flags[0] = se;
        flags[1] = sy;
        flags[2] = (scount < 900) ? 1 : 0;
    }
}

// ---- canonical weights: bf16 transposed WT[n][k] + fp32 biases -------------

__global__ void prep_weights(const void* __restrict__ W1l, const void* __restrict__ b1l,
                             const void* __restrict__ W1r, const void* __restrict__ W2l,
                             const void* __restrict__ b2l, const void* __restrict__ W2r,
                             const void* __restrict__ Wd, const int* __restrict__ flags,
                             short* __restrict__ T1l, short* __restrict__ T1r,
                             short* __restrict__ T2l, short* __restrict__ T2r,
                             short* __restrict__ Td, float* __restrict__ b1c,
                             float* __restrict__ b2c) {
    const int wf = flags[2];
    int idx = blockIdx.x * 256 + threadIdx.x;  // idx = k*128+n
    if (idx < NDIM * NDIM) {
        int k = idx >> 7, n = idx & 127;
        int o = n * NDIM + k;
        T1l[o] = f2bf(ldf(W1l, idx, wf));
        T1r[o] = f2bf(ldf(W1r, idx, wf));
        T2l[o] = f2bf(ldf(W2l, idx, wf));
        T2r[o] = f2bf(ldf(W2r, idx, wf));
        Td [o] = f2bf(ldf(Wd , idx, wf));
        if (idx < NDIM) { b1c[idx] = ldf(b1l, idx, wf); b2c[idx] = ldf(b2l, idx, wf); }
    }
}

// ---- CSR construction ------------------------------------------------------

__global__ void degree_kernel(const int* __restrict__ xedge, int E,
                              const int* __restrict__ flags, int* __restrict__ cnt) {
    int e = blockIdx.x * blockDim.x + threadIdx.x;
    if (e >= E) return;
    int d = flags[0] ? xedge[2 * (E + e)] : xedge[E + e];
    atomicAdd(&cnt[d], 1);
}

__global__ void scan_kernel(int* __restrict__ cnt, int* __restrict__ rowptr, int N) {
    __shared__ int part[1024];
    const int t = threadIdx.x;
    const int chunk = (N + 1023) >> 10;
    const int base = t * chunk;
    int s = 0;
    for (int i = 0; i < chunk; ++i) { int idx = base + i; if (idx < N) s += cnt[idx]; }
    part[t] = s;
    __syncthreads();
    for (int off = 1; off < 1024; off <<= 1) {
        int v = (t >= off) ? part[t - off] : 0;
        __syncthreads();
        part[t] += v;
        __syncthreads();
    }
    int run = (t == 0) ? 0 : part[t - 1];
    for (int i = 0; i < chunk; ++i) {
        int idx = base + i;
        if (idx < N) { rowptr[idx] = run; run += cnt[idx]; cnt[idx] = 0; }
    }
    if (t == 1023) rowptr[N] = part[1023];
}

__global__ void fill_kernel(const int* __restrict__ xedge, int E,
                            const int* __restrict__ flags, const int* __restrict__ rowptr,
                            int* __restrict__ cur, int* __restrict__ col) {
    int e = blockIdx.x * blockDim.x + threadIdx.x;
    if (e >= E) return;
    const int e64 = flags[0];
    int s = e64 ? xedge[2 * e] : xedge[e];
    int d = e64 ? xedge[2 * (E + e)] : xedge[E + e];
    int p = rowptr[d] + atomicAdd(&cur[d], 1);
    col[p] = s;
}

// ---- SAGE layer: gather-mean -> LDS bf16 -> MFMA dual-GEMM -----------------
// XMODE: 1 = input dtype follows flags[2]; 0 = input is canonical bf16.
// OUTMODE: 0 -> bf16 out (hbuf); 1 -> flag-dtype out at d_out + 1 element.

template <int XMODE, bool RELU, int OUTMODE>
__global__ __launch_bounds__(256)
void layer_mfma(const void* __restrict__ X, const int* __restrict__ rowptr,
                const int* __restrict__ col, const short* __restrict__ WlT,
                const float* __restrict__ biasc, const short* __restrict__ WrT,
                const int* __restrict__ flags, void* __restrict__ outp, int N) {
    __shared__ short Ms[32 * NDIM];
    __shared__ short Ss[32 * NDIM];
    const int t = threadIdx.x;
    const int n0 = blockIdx.x * 32;
    const int wf = flags[2];
    // ---- gather phase: 2 rows in flight, 128 feature-threads each ----
    {
        const int j = t & 127, g = t >> 7;
        for (int r = g; r < 32; r += 2) {
            int n = n0 + r;
            float m = 0.f, s = 0.f;
            if (n < N) {
                int b = rowptr[n], e = rowptr[n + 1];
                if (XMODE == 1 && wf) {
                    const float* Xf = (const float*)X;
                    for (int i = b; i < e; ++i) m += Xf[(long)col[i] * NDIM + j];
                    s = Xf[(long)n * NDIM + j];
                } else {
                    const __hip_bfloat16* Xh = (const __hip_bfloat16*)X;
                    for (int i = b; i < e; ++i) m += bf2f(Xh[(long)col[i] * NDIM + j]);
                    s = bf2f(Xh[(long)n * NDIM + j]);
                }
                m /= fmaxf((float)(e - b), 1.f);
            }
            Ms[aswz(r, j)] = f2bf(m);
            Ss[aswz(r, j)] = f2bf(s);
        }
    }
    __syncthreads();
    // ---- MFMA phase: wave w owns cols [w*32, w*32+32), 2x2 16x16 tiles ----
    const int l = t & 63, w = t >> 6;
    const int quad = l >> 4, l15 = l & 15;
    const int wcol = w * 32;
    f32x4 acc[2][2] = {};
    for (int k0 = 0; k0 < NDIM; k0 += 32) {
        const int kc = k0 + quad * 8;
        short8 ams[2], ass[2], bl[2], br[2];
#pragma unroll
        for (int rt = 0; rt < 2; ++rt) {
            int m = rt * 16 + l15;
            ams[rt] = *(const short8*)&Ms[aswz(m, kc)];
            ass[rt] = *(const short8*)&Ss[aswz(m, kc)];
        }
#pragma unroll
        for (int ct = 0; ct < 2; ++ct) {
            int n = wcol + ct * 16 + l15;
            bl[ct] = *(const short8*)&WlT[n * NDIM + kc];
            br[ct] = *(const short8*)&WrT[n * NDIM + kc];
        }
#pragma unroll
        for (int rt = 0; rt < 2; ++rt)
#pragma unroll
            for (int ct = 0; ct < 2; ++ct) {
                acc[rt][ct] = __builtin_amdgcn_mfma_f32_16x16x32_bf16(
                    ams[rt], bl[ct], acc[rt][ct], 0, 0, 0);
                acc[rt][ct] = __builtin_amdgcn_mfma_f32_16x16x32_bf16(
                    ass[rt], br[ct], acc[rt][ct], 0, 0, 0);
            }
    }
    // ---- epilogue: C/D layout col=lane&15, row=quad*4+reg (m89-verified) ----
#pragma unroll
    for (int ct = 0; ct < 2; ++ct) {
        int cg = wcol + ct * 16 + l15;
        float bv = biasc[cg];
#pragma unroll
        for (int rt = 0; rt < 2; ++rt)
#pragma unroll
            for (int reg = 0; reg < 4; ++reg) {
                int n = n0 + rt * 16 + quad * 4 + reg;
                if (n < N) {
                    float v = acc[rt][ct][reg] + bv;
                    if (RELU) v = fmaxf(v, 0.f);
                    if (OUTMODE == 0)
                        ((__hip_bfloat16*)outp)[(long)n * NDIM + cg] = __float2bfloat16(v);
                    else
                        stf((char*)outp + (wf ? 4 : 2), (long)n * NDIM + cg, wf, v);
                }
            }
    }
}

// ---- decoder GEMM + BCE-with-logits, MFMA ----------------------------------

__global__ __launch_bounds__(256)
void loss_mfma(const void* __restrict__ d_out_base, const short* __restrict__ WdT,
               const void* __restrict__ yv, const int* __restrict__ flags,
               float* __restrict__ accum, int* __restrict__ npos, int N) {
    __shared__ short As[32 * NDIM];
    __shared__ int ylds[32];
    __shared__ float red[4][2];
    const int t = threadIdx.x;
    const int n0 = blockIdx.x * 32;
    const int wf = flags[2], yb = flags[1];
    const void* emb = (const void*)((const char*)d_out_base + (wf ? 4 : 2));
    {
        const int j = t & 127, g = t >> 7;
        for (int r = g; r < 32; r += 2) {
            int n = n0 + r;
            float v = (n < N) ? ldf(emb, (long)n * NDIM + j, wf) : 0.f;
            As[aswz(r, j)] = f2bf(v);
        }
        if (t < 32) {
            int n = n0 + t;
            int yn = -1;
            if (n < N)
                yn = yb ? (int)((const unsigned char*)yv)[n]
                        : (((const int*)yv)[n] != 0 ? 1 : 0);
            ylds[t] = yn;
        }
    }
    __syncthreads();
    const int l = t & 63, w = t >> 6;
    const int quad = l >> 4, l15 = l & 15;
    const int wcol = w * 32;
    f32x4 acc[2][2] = {};
    for (int k0 = 0; k0 < NDIM; k0 += 32) {
        const int kc = k0 + quad * 8;
        short8 a[2], b[2];
#pragma unroll
        for (int rt = 0; rt < 2; ++rt)
            a[rt] = *(const short8*)&As[aswz(rt * 16 + l15, kc)];
#pragma unroll
        for (int ct = 0; ct < 2; ++ct)
            b[ct] = *(const short8*)&WdT[(wcol + ct * 16 + l15) * NDIM + kc];
#pragma unroll
        for (int rt = 0; rt < 2; ++rt)
#pragma unroll
            for (int ct = 0; ct < 2; ++ct)
                acc[rt][ct] = __builtin_amdgcn_mfma_f32_16x16x32_bf16(
                    a[rt], b[ct], acc[rt][ct], 0, 0, 0);
    }
    float lpos = 0.f, lneg = 0.f;
#pragma unroll
    for (int rt = 0; rt < 2; ++rt)
#pragma unroll
        for (int reg = 0; reg < 4; ++reg) {
            int row = rt * 16 + quad * 4 + reg;
            int yn = ylds[row];
            if (yn >= 0) {
#pragma unroll
                for (int ct = 0; ct < 2; ++ct) {
                    float z = acc[rt][ct][reg];
                    float L = log1pf(expf(-fabsf(z)));
                    if (yn) lpos += fmaxf(-z, 0.f) + L;   // softplus(-z)
                    else    lneg += fmaxf(z, 0.f) + L;    // softplus(z)
                }
            }
        }
#pragma unroll
    for (int off = 32; off >= 1; off >>= 1) {
        lpos += __shfl_down(lpos, off, 64);
        lneg += __shfl_down(lneg, off, 64);
    }
    if (l == 0) { red[w][0] = lpos; red[w][1] = lneg; }
    __syncthreads();
    if (t == 0) {
        atomicAdd(&accum[0], red[0][0] + red[1][0] + red[2][0] + red[3][0]);
        atomicAdd(&accum[1], red[0][1] + red[1][1] + red[2][1] + red[3][1]);
        int c = 0;
        for (int i = 0; i < 32; ++i) if (ylds[i] > 0) c++;
        if (c) atomicAdd(npos, c);
    }
}

__global__ void finalize_kernel(const float* __restrict__ accum, const int* __restrict__ npos,
                                const int* __restrict__ flags, void* __restrict__ out, int N) {
    float np_ = (float)(*npos);
    float nn_ = (float)N - np_;
    float l2 = accum[0] / (fmaxf(np_, 1.f) * 128.f);
    float l1 = accum[1] / (fmaxf(nn_, 1.f) * 128.f);
    stf(out, 0, flags[2], l1 + l2);
}

// ---- launch ----------------------------------------------------------------

extern "C" void kernel_launch(void* const* d_in, const int* in_sizes, int n_in,
                              void* d_out, int out_size, void* d_ws, size_t ws_size,
                              hipStream_t stream) {
    const void* x    = d_in[0];
    const int* xedge = (const int*)d_in[1];
    const void* y    = d_in[2];
    const void* W1l  = d_in[4];
    const void* b1l  = d_in[5];
    const void* W1r  = d_in[6];
    const void* W2l  = d_in[7];
    const void* b2l  = d_in[8];
    const void* W2r  = d_in[9];
    const void* Wdec = d_in[10];

    const int N = in_sizes[0] / NDIM;
    const int E = in_sizes[1] / 2;

    char* ws = (char*)d_ws;
    size_t off = 0;
    auto alloc = [&](size_t bytes) -> void* {
        void* p = ws + off;
        off = (off + bytes + 255) & ~(size_t)255;
        return p;
    };
    int*   flags  = (int*)alloc(64);
    float* accum  = (float*)alloc(64);
    int*   npos   = (int*)alloc(64);
    int*   cnt    = (int*)alloc((size_t)N * 4);
    int*   rowptr = (int*)alloc((size_t)(N + 1) * 4);
    int*   col    = (int*)alloc((size_t)E * 4);
    __hip_bfloat16* hbuf = (__hip_bfloat16*)alloc((size_t)N * NDIM * 2);
    short* T1l = (short*)alloc(NDIM * NDIM * 2);
    short* T1r = (short*)alloc(NDIM * NDIM * 2);
    short* T2l = (short*)alloc(NDIM * NDIM * 2);
    short* T2r = (short*)alloc(NDIM * NDIM * 2);
    short* Td  = (short*)alloc(NDIM * NDIM * 2);
    float* b1c = (float*)alloc(NDIM * 4);
    float* b2c = (float*)alloc(NDIM * 4);
    // total ws ~16.8 MB

    hipMemsetAsync(cnt, 0, (size_t)N * 4, stream);
    hipMemsetAsync(accum, 0, 8, stream);
    hipMemsetAsync(npos, 0, 4, stream);

    detect_kernel<<<1, 256, 0, stream>>>(xedge, (const unsigned int*)y,
                                         (const unsigned short*)x, flags);
    prep_weights<<<(NDIM * NDIM + 255) / 256, 256, 0, stream>>>(
        W1l, b1l, W1r, W2l, b2l, W2r, Wdec, flags, T1l, T1r, T2l, T2r, Td, b1c, b2c);

    const int eb = (E + 255) / 256;
    degree_kernel<<<eb, 256, 0, stream>>>(xedge, E, flags, cnt);
    scan_kernel<<<1, 1024, 0, stream>>>(cnt, rowptr, N);
    fill_kernel<<<eb, 256, 0, stream>>>(xedge, E, flags, rowptr, cnt, col);

    const int nb32 = (N + 31) / 32;
    layer_mfma<1, true, 0><<<nb32, 256, 0, stream>>>(
        x, rowptr, col, T1l, b1c, T1r, flags, hbuf, N);
    layer_mfma<0, false, 1><<<nb32, 256, 0, stream>>>(
        hbuf, rowptr, col, T2l, b2c, T2r, flags, d_out, N);
    loss_mfma<<<nb32, 256, 0, stream>>>(d_out, Td, y, flags, accum, npos, N);
    finalize_kernel<<<1, 1, 0, stream>>>(accum, npos, flags, d_out, N);
}

// Round 5
// 480.115 us; speedup vs baseline: 1.6466x; 1.5019x over previous
//
#include <hip/hip_runtime.h>
#include <hip/hip_bf16.h>

#define NDIM 128

typedef __attribute__((ext_vector_type(8))) short short8;
typedef __attribute__((ext_vector_type(4))) float f32x4;

__device__ __forceinline__ float bf2f(__hip_bfloat16 v) { return __bfloat162float(v); }

__device__ __forceinline__ float ldf(const void* p, long i, int f32) {
    return f32 ? ((const float*)p)[i] : bf2f(((const __hip_bfloat16*)p)[i]);
}
__device__ __forceinline__ void stf(void* p, long i, int f32, float v) {
    if (f32) ((float*)p)[i] = v;
    else     ((__hip_bfloat16*)p)[i] = __float2bfloat16(v);
}
__device__ __forceinline__ short f2bf(float v) {
    __hip_bfloat16 h = __float2bfloat16(v);
    short s;
    __builtin_memcpy(&s, &h, 2);
    return s;
}
// bf16x2 packed in a uint: low halfword = even feature, high = odd feature
__device__ __forceinline__ float bflo(unsigned u) { u <<= 16; float f; __builtin_memcpy(&f, &u, 4); return f; }
__device__ __forceinline__ float bfhi(unsigned u) { u &= 0xffff0000u; float f; __builtin_memcpy(&f, &u, 4); return f; }
__device__ __forceinline__ unsigned packbf(float a, float b) {
    unsigned la = (unsigned short)f2bf(a);
    unsigned hb = (unsigned short)f2bf(b);
    return (hb << 16) | la;
}
// Swizzled LDS index (shorts) for A-tiles: 16B-chunk XOR by (row&7).
__device__ __forceinline__ int aswz(int m, int k) {
    return m * NDIM + ((((k >> 3) ^ (m & 7)) << 3) | (k & 7));
}
// Same swizzle at uint (bf16x2) granularity: p = feature-pair index 0..63.
__device__ __forceinline__ int wswz(int m, int p) {
    return m * 64 + ((((p >> 2) ^ (m & 7)) << 2) | (p & 3));
}

// ---- detect dtypes + zero cnt/accum/npos -----------------------------------
// flags[0]=eflag (xedge int64), flags[1]=yflag (y byte-packed), flags[2]=fflag (fp32)
__global__ void detect_kernel(const int* __restrict__ xedge32,
                              const unsigned int* __restrict__ yw,
                              const unsigned short* __restrict__ xh,
                              int* __restrict__ flags, int* __restrict__ cnt,
                              float* __restrict__ accum, int* __restrict__ npos, int N) {
    const int gid = blockIdx.x * 256 + threadIdx.x;
    for (int i = gid; i < N; i += gridDim.x * 256) cnt[i] = 0;
    if (gid == 0) { accum[0] = 0.f; accum[1] = 0.f; npos[0] = 0; }
    if (blockIdx.x == 0) {
        __shared__ int se, sy, scount;
        const int t = threadIdx.x;
        if (t == 0) { se = 1; sy = 0; scount = 0; }
        __syncthreads();
        for (int i = t; i < 512; i += 256)
            if (xedge32[2 * i + 1] != 0) se = 0;
        for (int i = t; i < 1024; i += 256)
            if (yw[i] > 1u) sy = 1;
        int c = 0;
        for (int i = t; i < 1024; i += 256) {
            int ex = (xh[2 * i] >> 7) & 0xFF;
            if (ex >= 100 && ex <= 150) c++;
        }
        atomicAdd(&scount, c);
        __syncthreads();
        if (t == 0) { flags[0] = se; flags[1] = sy; flags[2] = (scount < 900) ? 1 : 0; }
    }
}

// ---- prep: bf16-transposed weights + fp32 biases + canonical bf16x2 x ------

__global__ void prep_kernel(const void* __restrict__ x,
                            const void* __restrict__ W1l, const void* __restrict__ b1l,
                            const void* __restrict__ W1r, const void* __restrict__ W2l,
                            const void* __restrict__ b2l, const void* __restrict__ W2r,
                            const void* __restrict__ Wd, const int* __restrict__ flags,
                            short* __restrict__ T1l, short* __restrict__ T1r,
                            short* __restrict__ T2l, short* __restrict__ T2r,
                            short* __restrict__ Td, float* __restrict__ b1c,
                            float* __restrict__ b2c, unsigned* __restrict__ xb, int N) {
    const int wf = flags[2];
    const long idx = (long)blockIdx.x * 256 + threadIdx.x;
    if (idx < NDIM * NDIM) {
        int k = (int)(idx >> 7), n = (int)(idx & 127);
        int o = n * NDIM + k;
        T1l[o] = f2bf(ldf(W1l, idx, wf));
        T1r[o] = f2bf(ldf(W1r, idx, wf));
        T2l[o] = f2bf(ldf(W2l, idx, wf));
        T2r[o] = f2bf(ldf(W2r, idx, wf));
        Td [o] = f2bf(ldf(Wd , idx, wf));
        if (idx < NDIM) { b1c[idx] = ldf(b1l, idx, wf); b2c[idx] = ldf(b2l, idx, wf); }
    } else {
        long p = idx - NDIM * NDIM;
        long np = (long)N * 64;
        if (p < np) {
            if (wf) {
                float2 v = ((const float2*)x)[p];
                xb[p] = packbf(v.x, v.y);
            } else {
                xb[p] = ((const unsigned*)x)[p];
            }
        }
    }
}

// ---- CSR construction ------------------------------------------------------

__global__ void degree_kernel(const int* __restrict__ xedge, int E,
                              const int* __restrict__ flags, int* __restrict__ cnt) {
    int e = blockIdx.x * blockDim.x + threadIdx.x;
    if (e >= E) return;
    int d = flags[0] ? xedge[2 * (E + e)] : xedge[E + e];
    atomicAdd(&cnt[d], 1);
}

__global__ void scan_kernel(int* __restrict__ cnt, int* __restrict__ rowptr, int N) {
    __shared__ int part[1024];
    const int t = threadIdx.x;
    const int chunk = (N + 1023) >> 10;
    const int base = t * chunk;
    int s = 0;
    for (int i = 0; i < chunk; ++i) { int idx = base + i; if (idx < N) s += cnt[idx]; }
    part[t] = s;
    __syncthreads();
    for (int off = 1; off < 1024; off <<= 1) {
        int v = (t >= off) ? part[t - off] : 0;
        __syncthreads();
        part[t] += v;
        __syncthreads();
    }
    int run = (t == 0) ? 0 : part[t - 1];
    for (int i = 0; i < chunk; ++i) {
        int idx = base + i;
        if (idx < N) { rowptr[idx] = run; run += cnt[idx]; cnt[idx] = 0; }
    }
    if (t == 1023) rowptr[N] = part[1023];
}

__global__ void fill_kernel(const int* __restrict__ xedge, int E,
                            const int* __restrict__ flags, const int* __restrict__ rowptr,
                            int* __restrict__ cur, int* __restrict__ col) {
    int e = blockIdx.x * blockDim.x + threadIdx.x;
    if (e >= E) return;
    const int e64 = flags[0];
    int s = e64 ? xedge[2 * e] : xedge[e];
    int d = e64 ? xedge[2 * (E + e)] : xedge[E + e];
    int p = rowptr[d] + atomicAdd(&cur[d], 1);
    col[p] = s;
}

// ---- SAGE layer: unrolled bf16x2 gather-mean -> LDS -> MFMA dual-GEMM ------
// Input is always a canonical bf16x2 buffer (xb or hbuf).
// OUTMODE: 0 -> bf16 out (hbuf); 1 -> flag-dtype out at d_out + 1 element.

template <bool RELU, int OUTMODE>
__global__ __launch_bounds__(256)
void layer_mfma(const unsigned* __restrict__ Xb, const int* __restrict__ rowptr,
                const int* __restrict__ col, const short* __restrict__ WlT,
                const float* __restrict__ biasc, const short* __restrict__ WrT,
                const int* __restrict__ flags, void* __restrict__ outp, int N) {
    __shared__ short Ms[32 * NDIM];
    __shared__ short Ss[32 * NDIM];
    unsigned* Msw = (unsigned*)Ms;
    unsigned* Ssw = (unsigned*)Ss;
    const int t = threadIdx.x;
    const int n0 = blockIdx.x * 32;
    const int wf = flags[2];
    // ---- gather: 4 row-groups of 64 lanes; lane = feature-pair; unroll 8 ----
    {
        const int g = t >> 6, p = t & 63;
        for (int r = g; r < 32; r += 4) {
            int n = n0 + r;
            float m0 = 0.f, m1 = 0.f;
            unsigned su = 0;
            if (n < N) {
                int b = rowptr[n], e = rowptr[n + 1];
                int i = b;
                for (; i + 8 <= e; i += 8) {
                    unsigned u0 = Xb[(long)col[i    ] * 64 + p];
                    unsigned u1 = Xb[(long)col[i + 1] * 64 + p];
                    unsigned u2 = Xb[(long)col[i + 2] * 64 + p];
                    unsigned u3 = Xb[(long)col[i + 3] * 64 + p];
                    unsigned u4 = Xb[(long)col[i + 4] * 64 + p];
                    unsigned u5 = Xb[(long)col[i + 5] * 64 + p];
                    unsigned u6 = Xb[(long)col[i + 6] * 64 + p];
                    unsigned u7 = Xb[(long)col[i + 7] * 64 + p];
                    m0 += ((bflo(u0) + bflo(u1)) + (bflo(u2) + bflo(u3)))
                        + ((bflo(u4) + bflo(u5)) + (bflo(u6) + bflo(u7)));
                    m1 += ((bfhi(u0) + bfhi(u1)) + (bfhi(u2) + bfhi(u3)))
                        + ((bfhi(u4) + bfhi(u5)) + (bfhi(u6) + bfhi(u7)));
                }
                for (; i < e; ++i) {
                    unsigned u = Xb[(long)col[i] * 64 + p];
                    m0 += bflo(u);
                    m1 += bfhi(u);
                }
                float inv = 1.f / fmaxf((float)(e - b), 1.f);
                m0 *= inv; m1 *= inv;
                su = Xb[(long)n * 64 + p];
            }
            int wi = wswz(r, p);
            Msw[wi] = packbf(m0, m1);
            Ssw[wi] = su;
        }
    }
    __syncthreads();
    // ---- MFMA: wave w owns cols [w*32, w*32+32), 2x2 16x16x32 tiles ----
    const int l = t & 63, w = t >> 6;
    const int quad = l >> 4, l15 = l & 15;
    const int wcol = w * 32;
    f32x4 acc[2][2] = {};
    for (int k0 = 0; k0 < NDIM; k0 += 32) {
        const int kc = k0 + quad * 8;
        short8 ams[2], ass[2], bl[2], br[2];
#pragma unroll
        for (int rt = 0; rt < 2; ++rt) {
            int m = rt * 16 + l15;
            ams[rt] = *(const short8*)&Ms[aswz(m, kc)];
            ass[rt] = *(const short8*)&Ss[aswz(m, kc)];
        }
#pragma unroll
        for (int ct = 0; ct < 2; ++ct) {
            int n = wcol + ct * 16 + l15;
            bl[ct] = *(const short8*)&WlT[n * NDIM + kc];
            br[ct] = *(const short8*)&WrT[n * NDIM + kc];
        }
#pragma unroll
        for (int rt = 0; rt < 2; ++rt)
#pragma unroll
            for (int ct = 0; ct < 2; ++ct) {
                acc[rt][ct] = __builtin_amdgcn_mfma_f32_16x16x32_bf16(
                    ams[rt], bl[ct], acc[rt][ct], 0, 0, 0);
                acc[rt][ct] = __builtin_amdgcn_mfma_f32_16x16x32_bf16(
                    ass[rt], br[ct], acc[rt][ct], 0, 0, 0);
            }
    }
    // ---- epilogue: C/D layout col=lane&15, row=quad*4+reg ----
#pragma unroll
    for (int ct = 0; ct < 2; ++ct) {
        int cg = wcol + ct * 16 + l15;
        float bv = biasc[cg];
#pragma unroll
        for (int rt = 0; rt < 2; ++rt)
#pragma unroll
            for (int reg = 0; reg < 4; ++reg) {
                int n = n0 + rt * 16 + quad * 4 + reg;
                if (n < N) {
                    float v = acc[rt][ct][reg] + bv;
                    if (RELU) v = fmaxf(v, 0.f);
                    if (OUTMODE == 0)
                        ((__hip_bfloat16*)outp)[(long)n * NDIM + cg] = __float2bfloat16(v);
                    else
                        stf((char*)outp + (wf ? 4 : 2), (long)n * NDIM + cg, wf, v);
                }
            }
    }
}

// ---- decoder GEMM + BCE-with-logits, MFMA ----------------------------------

__global__ __launch_bounds__(256)
void loss_mfma(const void* __restrict__ d_out_base, const short* __restrict__ WdT,
               const void* __restrict__ yv, const int* __restrict__ flags,
               float* __restrict__ accum, int* __restrict__ npos, int N) {
    __shared__ short As[32 * NDIM];
    __shared__ int ylds[32];
    __shared__ float red[4][2];
    const int t = threadIdx.x;
    const int n0 = blockIdx.x * 32;
    const int wf = flags[2], yb = flags[1];
    const void* emb = (const void*)((const char*)d_out_base + (wf ? 4 : 2));
    {
        const int j = t & 127, g = t >> 7;
        for (int r = g; r < 32; r += 2) {
            int n = n0 + r;
            float v = (n < N) ? ldf(emb, (long)n * NDIM + j, wf) : 0.f;
            As[aswz(r, j)] = f2bf(v);
        }
        if (t < 32) {
            int n = n0 + t;
            int yn = -1;
            if (n < N)
                yn = yb ? (int)((const unsigned char*)yv)[n]
                        : (((const int*)yv)[n] != 0 ? 1 : 0);
            ylds[t] = yn;
        }
    }
    __syncthreads();
    const int l = t & 63, w = t >> 6;
    const int quad = l >> 4, l15 = l & 15;
    const int wcol = w * 32;
    f32x4 acc[2][2] = {};
    for (int k0 = 0; k0 < NDIM; k0 += 32) {
        const int kc = k0 + quad * 8;
        short8 a[2], b[2];
#pragma unroll
        for (int rt = 0; rt < 2; ++rt)
            a[rt] = *(const short8*)&As[aswz(rt * 16 + l15, kc)];
#pragma unroll
        for (int ct = 0; ct < 2; ++ct)
            b[ct] = *(const short8*)&WdT[(wcol + ct * 16 + l15) * NDIM + kc];
#pragma unroll
        for (int rt = 0; rt < 2; ++rt)
#pragma unroll
            for (int ct = 0; ct < 2; ++ct)
                acc[rt][ct] = __builtin_amdgcn_mfma_f32_16x16x32_bf16(
                    a[rt], b[ct], acc[rt][ct], 0, 0, 0);
    }
    float lpos = 0.f, lneg = 0.f;
#pragma unroll
    for (int rt = 0; rt < 2; ++rt)
#pragma unroll
        for (int reg = 0; reg < 4; ++reg) {
            int row = rt * 16 + quad * 4 + reg;
            int yn = ylds[row];
            if (yn >= 0) {
#pragma unroll
                for (int ct = 0; ct < 2; ++ct) {
                    float z = acc[rt][ct][reg];
                    float L = log1pf(expf(-fabsf(z)));
                    if (yn) lpos += fmaxf(-z, 0.f) + L;
                    else    lneg += fmaxf(z, 0.f) + L;
                }
            }
        }
#pragma unroll
    for (int off = 32; off >= 1; off >>= 1) {
        lpos += __shfl_down(lpos, off, 64);
        lneg += __shfl_down(lneg, off, 64);
    }
    if (l == 0) { red[w][0] = lpos; red[w][1] = lneg; }
    __syncthreads();
    if (t == 0) {
        atomicAdd(&accum[0], red[0][0] + red[1][0] + red[2][0] + red[3][0]);
        atomicAdd(&accum[1], red[0][1] + red[1][1] + red[2][1] + red[3][1]);
        int c = 0;
        for (int i = 0; i < 32; ++i) if (ylds[i] > 0) c++;
        if (c) atomicAdd(npos, c);
    }
}

__global__ void finalize_kernel(const float* __restrict__ accum, const int* __restrict__ npos,
                                const int* __restrict__ flags, void* __restrict__ out, int N) {
    float np_ = (float)(*npos);
    float nn_ = (float)N - np_;
    float l2 = accum[0] / (fmaxf(np_, 1.f) * 128.f);
    float l1 = accum[1] / (fmaxf(nn_, 1.f) * 128.f);
    stf(out, 0, flags[2], l1 + l2);
}

// ---- launch ----------------------------------------------------------------

extern "C" void kernel_launch(void* const* d_in, const int* in_sizes, int n_in,
                              void* d_out, int out_size, void* d_ws, size_t ws_size,
                              hipStream_t stream) {
    const void* x    = d_in[0];
    const int* xedge = (const int*)d_in[1];
    const void* y    = d_in[2];
    const void* W1l  = d_in[4];
    const void* b1l  = d_in[5];
    const void* W1r  = d_in[6];
    const void* W2l  = d_in[7];
    const void* b2l  = d_in[8];
    const void* W2r  = d_in[9];
    const void* Wdec = d_in[10];

    const int N = in_sizes[0] / NDIM;
    const int E = in_sizes[1] / 2;

    char* ws = (char*)d_ws;
    size_t off = 0;
    auto alloc = [&](size_t bytes) -> void* {
        void* p = ws + off;
        off = (off + bytes + 255) & ~(size_t)255;
        return p;
    };
    int*   flags  = (int*)alloc(64);
    float* accum  = (float*)alloc(64);
    int*   npos   = (int*)alloc(64);
    int*   cnt    = (int*)alloc((size_t)N * 4);
    int*   rowptr = (int*)alloc((size_t)(N + 1) * 4);
    int*   col    = (int*)alloc((size_t)E * 4);
    unsigned* xb  = (unsigned*)alloc((size_t)N * 64 * 4);   // bf16x2 canonical x
    unsigned* hbuf = (unsigned*)alloc((size_t)N * 64 * 4);  // bf16x2 hidden
    short* T1l = (short*)alloc(NDIM * NDIM * 2);
    short* T1r = (short*)alloc(NDIM * NDIM * 2);
    short* T2l = (short*)alloc(NDIM * NDIM * 2);
    short* T2r = (short*)alloc(NDIM * NDIM * 2);
    short* Td  = (short*)alloc(NDIM * NDIM * 2);
    float* b1c = (float*)alloc(NDIM * 4);
    float* b2c = (float*)alloc(NDIM * 4);
    // total ws ~30 MB

    const int zb = (N + 255) / 256;
    detect_kernel<<<zb, 256, 0, stream>>>(xedge, (const unsigned int*)y,
                                          (const unsigned short*)x, flags, cnt,
                                          accum, npos, N);
    const long prep_items = (long)NDIM * NDIM + (long)N * 64;
    prep_kernel<<<(int)((prep_items + 255) / 256), 256, 0, stream>>>(
        x, W1l, b1l, W1r, W2l, b2l, W2r, Wdec, flags,
        T1l, T1r, T2l, T2r, Td, b1c, b2c, xb, N);

    const int eb = (E + 255) / 256;
    degree_kernel<<<eb, 256, 0, stream>>>(xedge, E, flags, cnt);
    scan_kernel<<<1, 1024, 0, stream>>>(cnt, rowptr, N);
    fill_kernel<<<eb, 256, 0, stream>>>(xedge, E, flags, rowptr, cnt, col);

    const int nb32 = (N + 31) / 32;
    layer_mfma<true, 0><<<nb32, 256, 0, stream>>>(
        xb, rowptr, col, T1l, b1c, T1r, flags, hbuf, N);
    layer_mfma<false, 1><<<nb32, 256, 0, stream>>>(
        hbuf, rowptr, col, T2l, b2c, T2r, flags, d_out, N);
    loss_mfma<<<nb32, 256, 0, stream>>>(d_out, Td, y, flags, accum, npos, N);
    finalize_kernel<<<1, 1, 0, stream>>>(accum, npos, flags, d_out, N);
}

// Round 6
// 364.363 us; speedup vs baseline: 2.1697x; 1.3177x over previous
//
#include <hip/hip_runtime.h>
#include <hip/hip_bf16.h>

#define NDIM 128
#define SCAN_CHUNK 1024  // per block: 256 threads x 4 elements

typedef __attribute__((ext_vector_type(8))) short short8;
typedef __attribute__((ext_vector_type(4))) float f32x4;

__device__ __forceinline__ float bf2f(__hip_bfloat16 v) { return __bfloat162float(v); }

__device__ __forceinline__ float ldf(const void* p, long i, int f32) {
    return f32 ? ((const float*)p)[i] : bf2f(((const __hip_bfloat16*)p)[i]);
}
__device__ __forceinline__ void stf(void* p, long i, int f32, float v) {
    if (f32) ((float*)p)[i] = v;
    else     ((__hip_bfloat16*)p)[i] = __float2bfloat16(v);
}
__device__ __forceinline__ short f2bf(float v) {
    __hip_bfloat16 h = __float2bfloat16(v);
    short s;
    __builtin_memcpy(&s, &h, 2);
    return s;
}
// bf16x2 packed in a uint: low halfword = even feature, high = odd feature
__device__ __forceinline__ float bflo(unsigned u) { u <<= 16; float f; __builtin_memcpy(&f, &u, 4); return f; }
__device__ __forceinline__ float bfhi(unsigned u) { u &= 0xffff0000u; float f; __builtin_memcpy(&f, &u, 4); return f; }
__device__ __forceinline__ unsigned packbf(float a, float b) {
    unsigned la = (unsigned short)f2bf(a);
    unsigned hb = (unsigned short)f2bf(b);
    return (hb << 16) | la;
}
// Swizzled LDS index (shorts) for A-tiles: 16B-chunk XOR by (row&7).
__device__ __forceinline__ int aswz(int m, int k) {
    return m * NDIM + ((((k >> 3) ^ (m & 7)) << 3) | (k & 7));
}
// Same swizzle at uint (bf16x2) granularity: p = feature-pair index 0..63.
__device__ __forceinline__ int wswz(int m, int p) {
    return m * 64 + ((((p >> 2) ^ (m & 7)) << 2) | (p & 3));
}

// ---- detect dtypes + zero cnt/accum/npos -----------------------------------
// flags[0]=eflag (xedge int64), flags[1]=yflag (y byte-packed), flags[2]=fflag (fp32)
__global__ void detect_kernel(const int* __restrict__ xedge32,
                              const unsigned int* __restrict__ yw,
                              const unsigned short* __restrict__ xh,
                              int* __restrict__ flags, int* __restrict__ cnt,
                              float* __restrict__ accum, int* __restrict__ npos, int N) {
    const int gid = blockIdx.x * 256 + threadIdx.x;
    for (int i = gid; i < N; i += gridDim.x * 256) cnt[i] = 0;
    if (gid == 0) { accum[0] = 0.f; accum[1] = 0.f; npos[0] = 0; }
    if (blockIdx.x == 0) {
        __shared__ int se, sy, scount;
        const int t = threadIdx.x;
        if (t == 0) { se = 1; sy = 0; scount = 0; }
        __syncthreads();
        for (int i = t; i < 512; i += 256)
            if (xedge32[2 * i + 1] != 0) se = 0;
        for (int i = t; i < 1024; i += 256)
            if (yw[i] > 1u) sy = 1;
        int c = 0;
        for (int i = t; i < 1024; i += 256) {
            int ex = (xh[2 * i] >> 7) & 0xFF;
            if (ex >= 100 && ex <= 150) c++;
        }
        atomicAdd(&scount, c);
        __syncthreads();
        if (t == 0) { flags[0] = se; flags[1] = sy; flags[2] = (scount < 900) ? 1 : 0; }
    }
}

// ---- prep: bf16-transposed weights + fp32 biases + canonical bf16x2 x ------

__global__ void prep_kernel(const void* __restrict__ x,
                            const void* __restrict__ W1l, const void* __restrict__ b1l,
                            const void* __restrict__ W1r, const void* __restrict__ W2l,
                            const void* __restrict__ b2l, const void* __restrict__ W2r,
                            const void* __restrict__ Wd, const int* __restrict__ flags,
                            short* __restrict__ T1l, short* __restrict__ T1r,
                            short* __restrict__ T2l, short* __restrict__ T2r,
                            short* __restrict__ Td, float* __restrict__ b1c,
                            float* __restrict__ b2c, unsigned* __restrict__ xb, int N) {
    const int wf = flags[2];
    const long idx = (long)blockIdx.x * 256 + threadIdx.x;
    if (idx < NDIM * NDIM) {
        int k = (int)(idx >> 7), n = (int)(idx & 127);
        int o = n * NDIM + k;
        T1l[o] = f2bf(ldf(W1l, idx, wf));
        T1r[o] = f2bf(ldf(W1r, idx, wf));
        T2l[o] = f2bf(ldf(W2l, idx, wf));
        T2r[o] = f2bf(ldf(W2r, idx, wf));
        Td [o] = f2bf(ldf(Wd , idx, wf));
        if (idx < NDIM) { b1c[idx] = ldf(b1l, idx, wf); b2c[idx] = ldf(b2l, idx, wf); }
    } else {
        long p = idx - NDIM * NDIM;
        long np = (long)N * 64;
        if (p < np) {
            if (wf) {
                float2 v = ((const float2*)x)[p];
                xb[p] = packbf(v.x, v.y);
            } else {
                xb[p] = ((const unsigned*)x)[p];
            }
        }
    }
}

// ---- CSR construction ------------------------------------------------------

__global__ void degree_kernel(const int* __restrict__ xedge, int E,
                              const int* __restrict__ flags, int* __restrict__ cnt) {
    int e = blockIdx.x * blockDim.x + threadIdx.x;
    if (e >= E) return;
    int d = flags[0] ? xedge[2 * (E + e)] : xedge[E + e];
    atomicAdd(&cnt[d], 1);
}

// ---- 3-phase multi-block exclusive scan of cnt -> rowptr -------------------

__global__ void scan_partial(const int* __restrict__ cnt, int* __restrict__ bsum, int N) {
    __shared__ int red[256];
    const int t = threadIdx.x;
    const long base = (long)blockIdx.x * SCAN_CHUNK + (long)t * 4;
    int s = 0;
#pragma unroll
    for (int i = 0; i < 4; ++i) { long idx = base + i; if (idx < N) s += cnt[idx]; }
    red[t] = s;
    __syncthreads();
    for (int off = 128; off >= 1; off >>= 1) {
        if (t < off) red[t] += red[t + off];
        __syncthreads();
    }
    if (t == 0) bsum[blockIdx.x] = red[0];
}

// single 1024-thread block: exclusive scan of up to 1024 block sums,
// writes boff[] and the grand total into rowptr[N].
__global__ void scan_bsums(const int* __restrict__ bsum, int* __restrict__ boff,
                           int B, int* __restrict__ rowptr, int N) {
    __shared__ int part[1024];
    const int t = threadIdx.x;
    int v = (t < B) ? bsum[t] : 0;
    part[t] = v;
    __syncthreads();
    for (int off = 1; off < 1024; off <<= 1) {
        int u = (t >= off) ? part[t - off] : 0;
        __syncthreads();
        part[t] += u;
        __syncthreads();
    }
    if (t < B) boff[t] = part[t] - v;  // exclusive
    if (t == 1023) rowptr[N] = part[1023];
}

__global__ void scan_scatter(int* __restrict__ cnt, const int* __restrict__ boff,
                             int* __restrict__ rowptr, int N) {
    __shared__ int tsum[256];
    const int t = threadIdx.x;
    const long base = (long)blockIdx.x * SCAN_CHUNK + (long)t * 4;
    int loc[4];
    int s = 0;
#pragma unroll
    for (int i = 0; i < 4; ++i) {
        long idx = base + i;
        int c = (idx < N) ? cnt[idx] : 0;
        loc[i] = s;
        s += c;
    }
    tsum[t] = s;
    __syncthreads();
    for (int off = 1; off < 256; off <<= 1) {
        int u = (t >= off) ? tsum[t - off] : 0;
        __syncthreads();
        tsum[t] += u;
        __syncthreads();
    }
    const int texcl = tsum[t] - s;
    const int b0 = boff[blockIdx.x];
#pragma unroll
    for (int i = 0; i < 4; ++i) {
        long idx = base + i;
        if (idx < N) { rowptr[idx] = b0 + texcl + loc[i]; cnt[idx] = 0; }
    }
}

__global__ void fill_kernel(const int* __restrict__ xedge, int E,
                            const int* __restrict__ flags, const int* __restrict__ rowptr,
                            int* __restrict__ cur, int* __restrict__ col) {
    int e = blockIdx.x * blockDim.x + threadIdx.x;
    if (e >= E) return;
    const int e64 = flags[0];
    int s = e64 ? xedge[2 * e] : xedge[e];
    int d = e64 ? xedge[2 * (E + e)] : xedge[E + e];
    int p = rowptr[d] + atomicAdd(&cur[d], 1);
    col[p] = s;
}

// ---- SAGE layer: unrolled bf16x2 gather-mean -> LDS -> MFMA dual-GEMM ------
// Input is always a canonical bf16x2 buffer (xb or hbuf).
// OUTMODE: 0 -> bf16 out (hbuf); 1 -> flag-dtype out at d_out + 1 element.

template <bool RELU, int OUTMODE>
__global__ __launch_bounds__(256)
void layer_mfma(const unsigned* __restrict__ Xb, const int* __restrict__ rowptr,
                const int* __restrict__ col, const short* __restrict__ WlT,
                const float* __restrict__ biasc, const short* __restrict__ WrT,
                const int* __restrict__ flags, void* __restrict__ outp, int N) {
    __shared__ short Ms[32 * NDIM];
    __shared__ short Ss[32 * NDIM];
    unsigned* Msw = (unsigned*)Ms;
    unsigned* Ssw = (unsigned*)Ss;
    const int t = threadIdx.x;
    const int n0 = blockIdx.x * 32;
    const int wf = flags[2];
    // ---- gather: 4 row-groups of 64 lanes; lane = feature-pair; unroll 8 ----
    {
        const int g = t >> 6, p = t & 63;
        for (int r = g; r < 32; r += 4) {
            int n = n0 + r;
            float m0 = 0.f, m1 = 0.f;
            unsigned su = 0;
            if (n < N) {
                int b = rowptr[n], e = rowptr[n + 1];
                int i = b;
                for (; i + 8 <= e; i += 8) {
                    unsigned u0 = Xb[(long)col[i    ] * 64 + p];
                    unsigned u1 = Xb[(long)col[i + 1] * 64 + p];
                    unsigned u2 = Xb[(long)col[i + 2] * 64 + p];
                    unsigned u3 = Xb[(long)col[i + 3] * 64 + p];
                    unsigned u4 = Xb[(long)col[i + 4] * 64 + p];
                    unsigned u5 = Xb[(long)col[i + 5] * 64 + p];
                    unsigned u6 = Xb[(long)col[i + 6] * 64 + p];
                    unsigned u7 = Xb[(long)col[i + 7] * 64 + p];
                    m0 += ((bflo(u0) + bflo(u1)) + (bflo(u2) + bflo(u3)))
                        + ((bflo(u4) + bflo(u5)) + (bflo(u6) + bflo(u7)));
                    m1 += ((bfhi(u0) + bfhi(u1)) + (bfhi(u2) + bfhi(u3)))
                        + ((bfhi(u4) + bfhi(u5)) + (bfhi(u6) + bfhi(u7)));
                }
                for (; i < e; ++i) {
                    unsigned u = Xb[(long)col[i] * 64 + p];
                    m0 += bflo(u);
                    m1 += bfhi(u);
                }
                float inv = 1.f / fmaxf((float)(e - b), 1.f);
                m0 *= inv; m1 *= inv;
                su = Xb[(long)n * 64 + p];
            }
            int wi = wswz(r, p);
            Msw[wi] = packbf(m0, m1);
            Ssw[wi] = su;
        }
    }
    __syncthreads();
    // ---- MFMA: wave w owns cols [w*32, w*32+32), 2x2 16x16x32 tiles ----
    const int l = t & 63, w = t >> 6;
    const int quad = l >> 4, l15 = l & 15;
    const int wcol = w * 32;
    f32x4 acc[2][2] = {};
    for (int k0 = 0; k0 < NDIM; k0 += 32) {
        const int kc = k0 + quad * 8;
        short8 ams[2], ass[2], bl[2], br[2];
#pragma unroll
        for (int rt = 0; rt < 2; ++rt) {
            int m = rt * 16 + l15;
            ams[rt] = *(const short8*)&Ms[aswz(m, kc)];
            ass[rt] = *(const short8*)&Ss[aswz(m, kc)];
        }
#pragma unroll
        for (int ct = 0; ct < 2; ++ct) {
            int n = wcol + ct * 16 + l15;
            bl[ct] = *(const short8*)&WlT[n * NDIM + kc];
            br[ct] = *(const short8*)&WrT[n * NDIM + kc];
        }
#pragma unroll
        for (int rt = 0; rt < 2; ++rt)
#pragma unroll
            for (int ct = 0; ct < 2; ++ct) {
                acc[rt][ct] = __builtin_amdgcn_mfma_f32_16x16x32_bf16(
                    ams[rt], bl[ct], acc[rt][ct], 0, 0, 0);
                acc[rt][ct] = __builtin_amdgcn_mfma_f32_16x16x32_bf16(
                    ass[rt], br[ct], acc[rt][ct], 0, 0, 0);
            }
    }
    // ---- epilogue: C/D layout col=lane&15, row=quad*4+reg ----
#pragma unroll
    for (int ct = 0; ct < 2; ++ct) {
        int cg = wcol + ct * 16 + l15;
        float bv = biasc[cg];
#pragma unroll
        for (int rt = 0; rt < 2; ++rt)
#pragma unroll
            for (int reg = 0; reg < 4; ++reg) {
                int n = n0 + rt * 16 + quad * 4 + reg;
                if (n < N) {
                    float v = acc[rt][ct][reg] + bv;
                    if (RELU) v = fmaxf(v, 0.f);
                    if (OUTMODE == 0)
                        ((__hip_bfloat16*)outp)[(long)n * NDIM + cg] = __float2bfloat16(v);
                    else
                        stf((char*)outp + (wf ? 4 : 2), (long)n * NDIM + cg, wf, v);
                }
            }
    }
}

// ---- decoder GEMM + BCE-with-logits, MFMA ----------------------------------

__global__ __launch_bounds__(256)
void loss_mfma(const void* __restrict__ d_out_base, const short* __restrict__ WdT,
               const void* __restrict__ yv, const int* __restrict__ flags,
               float* __restrict__ accum, int* __restrict__ npos, int N) {
    __shared__ short As[32 * NDIM];
    __shared__ int ylds[32];
    __shared__ float red[4][2];
    const int t = threadIdx.x;
    const int n0 = blockIdx.x * 32;
    const int wf = flags[2], yb = flags[1];
    const void* emb = (const void*)((const char*)d_out_base + (wf ? 4 : 2));
    {
        const int j = t & 127, g = t >> 7;
        for (int r = g; r < 32; r += 2) {
            int n = n0 + r;
            float v = (n < N) ? ldf(emb, (long)n * NDIM + j, wf) : 0.f;
            As[aswz(r, j)] = f2bf(v);
        }
        if (t < 32) {
            int n = n0 + t;
            int yn = -1;
            if (n < N)
                yn = yb ? (int)((const unsigned char*)yv)[n]
                        : (((const int*)yv)[n] != 0 ? 1 : 0);
            ylds[t] = yn;
        }
    }
    __syncthreads();
    const int l = t & 63, w = t >> 6;
    const int quad = l >> 4, l15 = l & 15;
    const int wcol = w * 32;
    f32x4 acc[2][2] = {};
    for (int k0 = 0; k0 < NDIM; k0 += 32) {
        const int kc = k0 + quad * 8;
        short8 a[2], b[2];
#pragma unroll
        for (int rt = 0; rt < 2; ++rt)
            a[rt] = *(const short8*)&As[aswz(rt * 16 + l15, kc)];
#pragma unroll
        for (int ct = 0; ct < 2; ++ct)
            b[ct] = *(const short8*)&WdT[(wcol + ct * 16 + l15) * NDIM + kc];
#pragma unroll
        for (int rt = 0; rt < 2; ++rt)
#pragma unroll
            for (int ct = 0; ct < 2; ++ct)
                acc[rt][ct] = __builtin_amdgcn_mfma_f32_16x16x32_bf16(
                    a[rt], b[ct], acc[rt][ct], 0, 0, 0);
    }
    float lpos = 0.f, lneg = 0.f;
#pragma unroll
    for (int rt = 0; rt < 2; ++rt)
#pragma unroll
        for (int reg = 0; reg < 4; ++reg) {
            int row = rt * 16 + quad * 4 + reg;
            int yn = ylds[row];
            if (yn >= 0) {
#pragma unroll
                for (int ct = 0; ct < 2; ++ct) {
                    float z = acc[rt][ct][reg];
                    float L = log1pf(expf(-fabsf(z)));
                    if (yn) lpos += fmaxf(-z, 0.f) + L;
                    else    lneg += fmaxf(z, 0.f) + L;
                }
            }
        }
#pragma unroll
    for (int off = 32; off >= 1; off >>= 1) {
        lpos += __shfl_down(lpos, off, 64);
        lneg += __shfl_down(lneg, off, 64);
    }
    if (l == 0) { red[w][0] = lpos; red[w][1] = lneg; }
    __syncthreads();
    if (t == 0) {
        atomicAdd(&accum[0], red[0][0] + red[1][0] + red[2][0] + red[3][0]);
        atomicAdd(&accum[1], red[0][1] + red[1][1] + red[2][1] + red[3][1]);
        int c = 0;
        for (int i = 0; i < 32; ++i) if (ylds[i] > 0) c++;
        if (c) atomicAdd(npos, c);
    }
}

__global__ void finalize_kernel(const float* __restrict__ accum, const int* __restrict__ npos,
                                const int* __restrict__ flags, void* __restrict__ out, int N) {
    float np_ = (float)(*npos);
    float nn_ = (float)N - np_;
    float l2 = accum[0] / (fmaxf(np_, 1.f) * 128.f);
    float l1 = accum[1] / (fmaxf(nn_, 1.f) * 128.f);
    stf(out, 0, flags[2], l1 + l2);
}

// ---- launch ----------------------------------------------------------------

extern "C" void kernel_launch(void* const* d_in, const int* in_sizes, int n_in,
                              void* d_out, int out_size, void* d_ws, size_t ws_size,
                              hipStream_t stream) {
    const void* x    = d_in[0];
    const int* xedge = (const int*)d_in[1];
    const void* y    = d_in[2];
    const void* W1l  = d_in[4];
    const void* b1l  = d_in[5];
    const void* W1r  = d_in[6];
    const void* W2l  = d_in[7];
    const void* b2l  = d_in[8];
    const void* W2r  = d_in[9];
    const void* Wdec = d_in[10];

    const int N = in_sizes[0] / NDIM;
    const int E = in_sizes[1] / 2;

    char* ws = (char*)d_ws;
    size_t off = 0;
    auto alloc = [&](size_t bytes) -> void* {
        void* p = ws + off;
        off = (off + bytes + 255) & ~(size_t)255;
        return p;
    };
    int*   flags  = (int*)alloc(64);
    float* accum  = (float*)alloc(64);
    int*   npos   = (int*)alloc(64);
    int*   bsum   = (int*)alloc(1024 * 4);
    int*   boff   = (int*)alloc(1024 * 4);
    int*   cnt    = (int*)alloc((size_t)N * 4);
    int*   rowptr = (int*)alloc((size_t)(N + 1) * 4);
    int*   col    = (int*)alloc((size_t)E * 4);
    unsigned* xb  = (unsigned*)alloc((size_t)N * 64 * 4);   // bf16x2 canonical x
    unsigned* hbuf = (unsigned*)alloc((size_t)N * 64 * 4);  // bf16x2 hidden
    short* T1l = (short*)alloc(NDIM * NDIM * 2);
    short* T1r = (short*)alloc(NDIM * NDIM * 2);
    short* T2l = (short*)alloc(NDIM * NDIM * 2);
    short* T2r = (short*)alloc(NDIM * NDIM * 2);
    short* Td  = (short*)alloc(NDIM * NDIM * 2);
    float* b1c = (float*)alloc(NDIM * 4);
    float* b2c = (float*)alloc(NDIM * 4);
    // total ws ~30 MB

    const int zb = (N + 255) / 256;
    detect_kernel<<<zb, 256, 0, stream>>>(xedge, (const unsigned int*)y,
                                          (const unsigned short*)x, flags, cnt,
                                          accum, npos, N);
    const long prep_items = (long)NDIM * NDIM + (long)N * 64;
    prep_kernel<<<(int)((prep_items + 255) / 256), 256, 0, stream>>>(
        x, W1l, b1l, W1r, W2l, b2l, W2r, Wdec, flags,
        T1l, T1r, T2l, T2r, Td, b1c, b2c, xb, N);

    const int eb = (E + 255) / 256;
    degree_kernel<<<eb, 256, 0, stream>>>(xedge, E, flags, cnt);

    const int sb = (N + SCAN_CHUNK - 1) / SCAN_CHUNK;  // <=1024 blocks supported
    scan_partial<<<sb, 256, 0, stream>>>(cnt, bsum, N);
    scan_bsums<<<1, 1024, 0, stream>>>(bsum, boff, sb, rowptr, N);
    scan_scatter<<<sb, 256, 0, stream>>>(cnt, boff, rowptr, N);

    fill_kernel<<<eb, 256, 0, stream>>>(xedge, E, flags, rowptr, cnt, col);

    const int nb32 = (N + 31) / 32;
    layer_mfma<true, 0><<<nb32, 256, 0, stream>>>(
        xb, rowptr, col, T1l, b1c, T1r, flags, hbuf, N);
    layer_mfma<false, 1><<<nb32, 256, 0, stream>>>(
        hbuf, rowptr, col, T2l, b2c, T2r, flags, d_out, N);
    loss_mfma<<<nb32, 256, 0, stream>>>(d_out, Td, y, flags, accum, npos, N);
    finalize_kernel<<<1, 1, 0, stream>>>(accum, npos, flags, d_out, N);
}